// Round 1
// baseline (510.924 us; speedup 1.0000x reference)
//
#include <hip/hip_runtime.h>
#include <hip/hip_bf16.h>

using bf16x8 = __attribute__((ext_vector_type(8))) short;
using f32x4  = __attribute__((ext_vector_type(4))) float;

static __device__ __forceinline__ float bf2f(short s) {
  union { unsigned u; float f; } z;
  z.u = ((unsigned)(unsigned short)s) << 16;
  return z.f;
}
static __device__ __forceinline__ float frcp(float x) { return __builtin_amdgcn_rcpf(x); }
static __device__ __forceinline__ float sigm_f(float x) { return frcp(1.f + __expf(-x)); }
static __device__ __forceinline__ float tanh_f(float x) {
  float e = __expf(-2.f * fabsf(x));
  float t = (1.f - e) * frcp(1.f + e);
  return copysignf(t, x);
}

// ---------------------------------------------------------------------------
// K1: cheb [3][1024][1024] f32  ->  chebT bf16 [n][k*1024+m]
// ---------------------------------------------------------------------------
__global__ void __launch_bounds__(256) k_transpose_cheb(
    const float* __restrict__ cheb, __hip_bfloat16* __restrict__ chebT) {
  __shared__ float tile[64][65];
  int blk = blockIdx.x;
  int k = blk >> 8;            // 256 tiles per k
  int rem = blk & 255;
  int m0 = (rem >> 4) << 6;
  int n0 = (rem & 15) << 6;
  int tx = threadIdx.x & 63;
  int ty = threadIdx.x >> 6;   // 0..3
  const float* src = cheb + (size_t)k * 1024 * 1024;
  #pragma unroll
  for (int i = 0; i < 16; i++) {
    int ml = ty + i * 4;
    tile[ml][tx] = src[(size_t)(m0 + ml) * 1024 + n0 + tx];
  }
  __syncthreads();
  #pragma unroll
  for (int i = 0; i < 16; i++) {
    int nl = ty + i * 4;
    chebT[(size_t)(n0 + nl) * 3072 + k * 1024 + m0 + tx] =
        __float2bfloat16(tile[tx][nl]);
  }
}

// ---------------------------------------------------------------------------
// K2: fused TCN1 (1->64, gated) + w_cheb projection (64 -> 3*16)
//     writes HWT bf16 [btl][o][k*1024+m]   (chunk-local btl)
// ---------------------------------------------------------------------------
__global__ void __launch_bounds__(256) k_tcn1_proj(
    const float* __restrict__ x,
    const float* __restrict__ w1, const float* __restrict__ b1,
    const float* __restrict__ w2, const float* __restrict__ b2,
    const float* __restrict__ w3, const float* __restrict__ b3,
    const float* __restrict__ wcheb,
    __hip_bfloat16* __restrict__ hwt, int bt0) {
  __shared__ __align__(16) float s_w[576];   // [conv][c][dt]
  __shared__ float s_b[192];
  __shared__ __align__(16) float s_wc[3072]; // [k][c][o]
  int tid = threadIdx.x;
  for (int i = tid; i < 192; i += 256) {
    s_w[i] = w1[i]; s_w[192 + i] = w2[i]; s_w[384 + i] = w3[i];
  }
  if (tid < 64) { s_b[tid] = b1[tid]; s_b[64 + tid] = b2[tid]; s_b[128 + tid] = b3[tid]; }
  for (int i = tid; i < 3072; i += 256) s_wc[i] = wcheb[i];
  __syncthreads();

  int btl = blockIdx.x >> 2;
  int m = ((blockIdx.x & 3) << 8) + tid;
  int bt = bt0 + btl;
  int b = bt / 22, t = bt % 22;
  const float* xp = x + (size_t)(b * 24 + t) * 1024 + m;
  float x0 = xp[0], x1 = xp[1024], x2 = xp[2048];

  float acc[48];
  #pragma unroll
  for (int j = 0; j < 48; j++) acc[j] = 0.f;

  const float4* wc4 = reinterpret_cast<const float4*>(s_wc);
  for (int c = 0; c < 64; c++) {
    float p  = fmaf(x2, s_w[c*3+2],     fmaf(x1, s_w[c*3+1],     fmaf(x0, s_w[c*3+0],     s_b[c])));
    float qz = fmaf(x2, s_w[192+c*3+2], fmaf(x1, s_w[192+c*3+1], fmaf(x0, s_w[192+c*3+0], s_b[64+c])));
    float rz = fmaf(x2, s_w[384+c*3+2], fmaf(x1, s_w[384+c*3+1], fmaf(x0, s_w[384+c*3+0], s_b[128+c])));
    float h = fmaf(p, sigm_f(qz), tanh_f(rz));
    #pragma unroll
    for (int k = 0; k < 3; k++) {
      #pragma unroll
      for (int og = 0; og < 4; og++) {
        float4 w4 = wc4[k*256 + c*4 + og];
        acc[k*16+og*4+0] = fmaf(h, w4.x, acc[k*16+og*4+0]);
        acc[k*16+og*4+1] = fmaf(h, w4.y, acc[k*16+og*4+1]);
        acc[k*16+og*4+2] = fmaf(h, w4.z, acc[k*16+og*4+2]);
        acc[k*16+og*4+3] = fmaf(h, w4.w, acc[k*16+og*4+3]);
      }
    }
  }
  __hip_bfloat16* hp = hwt + (size_t)btl * 49152 + m;
  #pragma unroll
  for (int k = 0; k < 3; k++)
    #pragma unroll
    for (int o = 0; o < 16; o++)
      hp[o * 3072 + k * 1024] = __float2bfloat16(acc[k*16+o]);
}

// ---------------------------------------------------------------------------
// K3: batched GEMM  S[bt][n][o] = ChebT[n][km] * HWT[bt][o][km] + b_cheb[o]
//     block: 4 waves, 256 n-rows, 4 bt.  MFMA 16x16x32 bf16.
// ---------------------------------------------------------------------------
__global__ void __launch_bounds__(256) k_gemm(
    const __hip_bfloat16* __restrict__ chebT,
    const __hip_bfloat16* __restrict__ hwt,
    const float* __restrict__ b_cheb,
    __hip_bfloat16* __restrict__ sbuf,
    int bt_base, int nbt) {
  int tid = threadIdx.x;
  int lane = tid & 63;
  int w = tid >> 6;
  int nb = (blockIdx.x & 3) << 8;
  int btg = blockIdx.x >> 2;
  int row16 = lane & 15;   // A-row / B-col(o) / D-col
  int kb = lane >> 4;      // 0..3
  int n_base = nb + (w << 6);

  f32x4 acc[4][4];
  #pragma unroll
  for (int i = 0; i < 4; i++)
    #pragma unroll
    for (int j = 0; j < 4; j++) acc[i][j] = (f32x4){0.f, 0.f, 0.f, 0.f};

  const bf16x8* Ab[4];
  #pragma unroll
  for (int i = 0; i < 4; i++)
    Ab[i] = reinterpret_cast<const bf16x8*>(
        chebT + (size_t)(n_base + i * 16 + row16) * 3072 + kb * 8);
  const bf16x8* Bb[4];
  bool btv[4];
  #pragma unroll
  for (int j = 0; j < 4; j++) {
    int bl = btg * 4 + j;
    btv[j] = bl < nbt;
    int blc = btv[j] ? bl : 0;
    Bb[j] = reinterpret_cast<const bf16x8*>(
        hwt + (size_t)blc * 49152 + row16 * 3072 + kb * 8);
  }

  for (int ks = 0; ks < 96; ks++) {
    bf16x8 a[4], bf[4];
    #pragma unroll
    for (int i = 0; i < 4; i++) a[i] = Ab[i][ks * 4];
    #pragma unroll
    for (int j = 0; j < 4; j++) bf[j] = Bb[j][ks * 4];
    #pragma unroll
    for (int i = 0; i < 4; i++)
      #pragma unroll
      for (int j = 0; j < 4; j++)
        acc[i][j] = __builtin_amdgcn_mfma_f32_16x16x32_bf16(a[i], bf[j], acc[i][j], 0, 0, 0);
  }

  float bias = b_cheb[row16];
  #pragma unroll
  for (int j = 0; j < 4; j++) {
    if (!btv[j]) continue;
    size_t bt_g = (size_t)bt_base + btg * 4 + j;
    #pragma unroll
    for (int i = 0; i < 4; i++) {
      int n0 = n_base + i * 16 + kb * 4;   // D row = (lane>>4)*4 + r
      __hip_bfloat16* sp = sbuf + (bt_g * 1024 + n0) * 16 + row16;
      #pragma unroll
      for (int r = 0; r < 4; r++)
        sp[r * 16] = __float2bfloat16(acc[i][j][r] + bias);
    }
  }
}

// ---------------------------------------------------------------------------
// K4: fused TCN2 (16->16, gated), sbuf bf16 -> h2 f32 (= d_out, pre-BN)
// ---------------------------------------------------------------------------
__global__ void __launch_bounds__(256) k_tcn2(
    const __hip_bfloat16* __restrict__ sbuf,
    const float* __restrict__ w1, const float* __restrict__ b1,
    const float* __restrict__ w2, const float* __restrict__ b2,
    const float* __restrict__ w3, const float* __restrict__ b3,
    float* __restrict__ h2) {
  __shared__ __align__(16) float s_w[2304];  // [conv][dt][o][ci]
  __shared__ float s_b[48];
  int tid = threadIdx.x;
  for (int i = tid; i < 768; i += 256) {
    int o = i / 48; int r = i % 48; int ci = r / 3; int dt = r % 3;
    int dst = dt * 256 + o * 16 + ci;
    s_w[dst] = w1[i]; s_w[768 + dst] = w2[i]; s_w[1536 + dst] = w3[i];
  }
  if (tid < 16) { s_b[tid] = b1[tid]; s_b[16 + tid] = b2[tid]; s_b[32 + tid] = b3[tid]; }
  __syncthreads();

  int bt2 = blockIdx.x >> 2;                 // 0..639
  int n = ((blockIdx.x & 3) << 8) + tid;
  int b = bt2 / 20, t2 = bt2 % 20;

  float in[3][16];
  #pragma unroll
  for (int dt = 0; dt < 3; dt++) {
    const bf16x8* sp = reinterpret_cast<const bf16x8*>(
        sbuf + ((size_t)(b * 22 + t2 + dt) * 1024 + n) * 16);
    bf16x8 v0 = sp[0], v1 = sp[1];
    #pragma unroll
    for (int j = 0; j < 8; j++) { in[dt][j] = bf2f(v0[j]); in[dt][8 + j] = bf2f(v1[j]); }
  }

  const float4* w4 = reinterpret_cast<const float4*>(s_w);
  float res[16];
  #pragma unroll
  for (int o = 0; o < 16; o++) {
    float p = s_b[o], qz = s_b[16 + o], rz = s_b[32 + o];
    #pragma unroll
    for (int dt = 0; dt < 3; dt++) {
      #pragma unroll
      for (int cg = 0; cg < 4; cg++) {
        float4 wa = w4[(dt * 256 + o * 16) / 4 + cg];
        float4 wb = w4[(768 + dt * 256 + o * 16) / 4 + cg];
        float4 wc = w4[(1536 + dt * 256 + o * 16) / 4 + cg];
        const float* iv = &in[dt][cg * 4];
        p  = fmaf(iv[0], wa.x, fmaf(iv[1], wa.y, fmaf(iv[2], wa.z, fmaf(iv[3], wa.w, p))));
        qz = fmaf(iv[0], wb.x, fmaf(iv[1], wb.y, fmaf(iv[2], wb.z, fmaf(iv[3], wb.w, qz))));
        rz = fmaf(iv[0], wc.x, fmaf(iv[1], wc.y, fmaf(iv[2], wc.z, fmaf(iv[3], wc.w, rz))));
      }
    }
    res[o] = fmaf(p, sigm_f(qz), tanh_f(rz));
  }
  float4* hp = reinterpret_cast<float4*>(h2 + ((size_t)bt2 * 1024 + n) * 16);
  #pragma unroll
  for (int g = 0; g < 4; g++)
    hp[g] = (float4){res[g*4+0], res[g*4+1], res[g*4+2], res[g*4+3]};
}

// ---------------------------------------------------------------------------
// K5: per-node batch stats -> a[n], c[n]
// ---------------------------------------------------------------------------
__global__ void __launch_bounds__(256) k_stats(
    const float* __restrict__ h2, const float* __restrict__ gamma,
    const float* __restrict__ beta, float* __restrict__ ab) {
  int n = blockIdx.x;
  int tid = threadIdx.x;
  float s = 0.f, s2 = 0.f;
  int part = tid & 3;
  for (int bt2 = tid >> 2; bt2 < 640; bt2 += 64) {
    float4 v = *reinterpret_cast<const float4*>(h2 + ((size_t)bt2 * 1024 + n) * 16 + part * 4);
    s  += v.x + v.y + v.z + v.w;
    s2 += v.x*v.x + v.y*v.y + v.z*v.z + v.w*v.w;
  }
  #pragma unroll
  for (int off = 32; off; off >>= 1) { s += __shfl_down(s, off); s2 += __shfl_down(s2, off); }
  __shared__ float rs[4], rs2[4];
  if ((tid & 63) == 0) { rs[tid >> 6] = s; rs2[tid >> 6] = s2; }
  __syncthreads();
  if (tid == 0) {
    float S = rs[0] + rs[1] + rs[2] + rs[3];
    float S2 = rs2[0] + rs2[1] + rs2[2] + rs2[3];
    float mean = S * (1.f / 10240.f);
    float var = S2 * (1.f / 10240.f) - mean * mean;
    float a = gamma[n] * rsqrtf(var + 1e-5f);
    ab[n] = a;
    ab[1024 + n] = beta[n] - mean * a;
  }
}

// ---------------------------------------------------------------------------
// K6: in-place BN + ReLU on d_out
// ---------------------------------------------------------------------------
__global__ void __launch_bounds__(256) k_bnrelu(
    float* __restrict__ h2, const float* __restrict__ ab) {
  size_t i = (size_t)blockIdx.x * 256 + threadIdx.x;   // float4 index
  int n = (int)((i >> 2) & 1023);
  float a = ab[n], c = ab[1024 + n];
  float4* p = reinterpret_cast<float4*>(h2) + i;
  float4 v = *p;
  v.x = fmaxf(0.f, fmaf(v.x, a, c));
  v.y = fmaxf(0.f, fmaf(v.y, a, c));
  v.z = fmaxf(0.f, fmaf(v.z, a, c));
  v.w = fmaxf(0.f, fmaf(v.w, a, c));
  *p = v;
}

// ---------------------------------------------------------------------------
extern "C" void kernel_launch(void* const* d_in, const int* in_sizes, int n_in,
                              void* d_out, int out_size, void* d_ws, size_t ws_size,
                              hipStream_t stream) {
  const float* x     = (const float*)d_in[0];
  const float* cheb  = (const float*)d_in[1];
  const float* t1w1  = (const float*)d_in[2];
  const float* t1b1  = (const float*)d_in[3];
  const float* t1w2  = (const float*)d_in[4];
  const float* t1b2  = (const float*)d_in[5];
  const float* t1w3  = (const float*)d_in[6];
  const float* t1b3  = (const float*)d_in[7];
  const float* wch   = (const float*)d_in[8];
  const float* bch   = (const float*)d_in[9];
  const float* t2w1  = (const float*)d_in[10];
  const float* t2b1  = (const float*)d_in[11];
  const float* t2w2  = (const float*)d_in[12];
  const float* t2b2  = (const float*)d_in[13];
  const float* t2w3  = (const float*)d_in[14];
  const float* t2b3  = (const float*)d_in[15];
  const float* gam   = (const float*)d_in[16];
  const float* bet   = (const float*)d_in[17];

  char* ws = (char*)d_ws;
  __hip_bfloat16* chebT = (__hip_bfloat16*)ws;                   // 6,291,456 B
  __hip_bfloat16* sbuf  = (__hip_bfloat16*)(ws + 6291456);       // 23,068,672 B
  float*          ab    = (float*)(ws + 29360128);               // 8,192 B
  __hip_bfloat16* hwt   = (__hip_bfloat16*)(ws + 29368320);      // chunk buffer

  size_t avail = ws_size > 29368320 ? ws_size - 29368320 : 0;
  int maxch = (int)(avail / 98304);
  maxch &= ~3;
  if (maxch > 704) maxch = 704;
  if (maxch < 4) maxch = 4;

  k_transpose_cheb<<<768, 256, 0, stream>>>(cheb, chebT);

  for (int bt0 = 0; bt0 < 704; bt0 += maxch) {
    int ch = (704 - bt0 < maxch) ? (704 - bt0) : maxch;
    k_tcn1_proj<<<ch * 4, 256, 0, stream>>>(x, t1w1, t1b1, t1w2, t1b2, t1w3, t1b3,
                                            wch, hwt, bt0);
    k_gemm<<<ch, 256, 0, stream>>>(chebT, hwt, bch, sbuf, bt0, ch);
  }

  k_tcn2<<<640 * 4, 256, 0, stream>>>(sbuf, t2w1, t2b1, t2w2, t2b2, t2w3, t2b3,
                                      (float*)d_out);
  k_stats<<<1024, 256, 0, stream>>>((const float*)d_out, gam, bet, ab);
  k_bnrelu<<<10240, 256, 0, stream>>>((float*)d_out, ab);
}

// Round 2
// 317.453 us; speedup vs baseline: 1.6094x; 1.6094x over previous
//
#include <hip/hip_runtime.h>
#include <hip/hip_bf16.h>

using bf16x8 = __attribute__((ext_vector_type(8))) short;
using f32x4  = __attribute__((ext_vector_type(4))) float;

static __device__ __forceinline__ float bf2f(short s) {
  union { unsigned u; float f; } z;
  z.u = ((unsigned)(unsigned short)s) << 16;
  return z.f;
}
static __device__ __forceinline__ float frcp(float x) { return __builtin_amdgcn_rcpf(x); }
static __device__ __forceinline__ float sigm_f(float x) { return frcp(1.f + __expf(-x)); }
static __device__ __forceinline__ float tanh_f(float x) {
  float e = __expf(-2.f * fabsf(x));
  float t = (1.f - e) * frcp(1.f + e);
  return copysignf(t, x);
}

typedef const __attribute__((address_space(1))) unsigned int* gas_u32;
typedef __attribute__((address_space(3))) unsigned int* las_u32;
#define GLOAD16(gp, lp) __builtin_amdgcn_global_load_lds( \
    (gas_u32)(const void*)(gp), (las_u32)(void*)(lp), 16, 0, 0)

// ---------------------------------------------------------------------------
// K1: cheb [3][1024][1024] f32  ->  chebT bf16 [n][k*1024+m]
// ---------------------------------------------------------------------------
__global__ void __launch_bounds__(256) k_transpose_cheb(
    const float* __restrict__ cheb, __hip_bfloat16* __restrict__ chebT) {
  __shared__ float tile[64][65];
  int blk = blockIdx.x;
  int k = blk >> 8;
  int rem = blk & 255;
  int m0 = (rem >> 4) << 6;
  int n0 = (rem & 15) << 6;
  int tx = threadIdx.x & 63;
  int ty = threadIdx.x >> 6;
  const float* src = cheb + (size_t)k * 1024 * 1024;
  #pragma unroll
  for (int i = 0; i < 16; i++) {
    int ml = ty + i * 4;
    tile[ml][tx] = src[(size_t)(m0 + ml) * 1024 + n0 + tx];
  }
  __syncthreads();
  #pragma unroll
  for (int i = 0; i < 16; i++) {
    int nl = ty + i * 4;
    chebT[(size_t)(n0 + nl) * 3072 + k * 1024 + m0 + tx] =
        __float2bfloat16(tile[tx][nl]);
  }
}

// ---------------------------------------------------------------------------
// K2: fused TCN1 (1->64, gated) + w_cheb projection (64 -> 3*16)
//     weights read via wave-uniform global loads -> scalar (s_load) pipe
// ---------------------------------------------------------------------------
__global__ void __launch_bounds__(256) k_tcn1_proj(
    const float* __restrict__ x,
    const float* __restrict__ w1, const float* __restrict__ b1,
    const float* __restrict__ w2, const float* __restrict__ b2,
    const float* __restrict__ w3, const float* __restrict__ b3,
    const float* __restrict__ wcheb,
    __hip_bfloat16* __restrict__ hwt, int bt0) {
  int tid = threadIdx.x;
  int btl = blockIdx.x >> 2;
  int m = ((blockIdx.x & 3) << 8) + tid;
  int bt = bt0 + btl;
  int b = bt / 22, t = bt % 22;
  const float* xp = x + (size_t)(b * 24 + t) * 1024 + m;
  float x0 = xp[0], x1 = xp[1024], x2 = xp[2048];

  float acc[48];
  #pragma unroll
  for (int j = 0; j < 48; j++) acc[j] = 0.f;

  const float4* wc4 = reinterpret_cast<const float4*>(wcheb);
  #pragma unroll 2
  for (int c = 0; c < 64; c++) {
    float p  = fmaf(x2, w1[c*3+2], fmaf(x1, w1[c*3+1], fmaf(x0, w1[c*3+0], b1[c])));
    float qz = fmaf(x2, w2[c*3+2], fmaf(x1, w2[c*3+1], fmaf(x0, w2[c*3+0], b2[c])));
    float rz = fmaf(x2, w3[c*3+2], fmaf(x1, w3[c*3+1], fmaf(x0, w3[c*3+0], b3[c])));
    float h = fmaf(p, sigm_f(qz), tanh_f(rz));
    #pragma unroll
    for (int k = 0; k < 3; k++) {
      #pragma unroll
      for (int og = 0; og < 4; og++) {
        float4 w4 = wc4[k*256 + c*4 + og];
        acc[k*16+og*4+0] = fmaf(h, w4.x, acc[k*16+og*4+0]);
        acc[k*16+og*4+1] = fmaf(h, w4.y, acc[k*16+og*4+1]);
        acc[k*16+og*4+2] = fmaf(h, w4.z, acc[k*16+og*4+2]);
        acc[k*16+og*4+3] = fmaf(h, w4.w, acc[k*16+og*4+3]);
      }
    }
  }
  __hip_bfloat16* hp = hwt + (size_t)btl * 49152 + m;
  #pragma unroll
  for (int k = 0; k < 3; k++)
    #pragma unroll
    for (int o = 0; o < 16; o++)
      hp[o * 3072 + k * 1024] = __float2bfloat16(acc[k*16+o]);
}

// ---------------------------------------------------------------------------
// K3: tiled GEMM  S[bt][n][o] = ChebT[n][km] * HWT[bt][o][km] + b_cheb[o]
//     128x128 tile (BM=128 n-rows, BN=128 = 8bt x 16o), BK=64.
//     4 waves (2x2). LDS: A[128][64] + B[128][64] bf16, 128B/row,
//     XOR-swizzle ((row&7)<<4) via pre-swizzled global source (rule #21).
//     Grid: blockIdx = ct*8 + nt  (nt = n-tile -> XCD-resident A panel).
// ---------------------------------------------------------------------------
__global__ void __launch_bounds__(256, 2) k_gemm(
    const __hip_bfloat16* __restrict__ chebT,
    const __hip_bfloat16* __restrict__ hwt,
    const float* __restrict__ b_cheb,
    __hip_bfloat16* __restrict__ sbuf,
    int bt_base) {
  __shared__ __align__(16) char smem[32768];
  const int tid = threadIdx.x;
  const int lane = tid & 63;
  const int w = tid >> 6;
  const int nt = blockIdx.x & 7;
  const int ct = blockIdx.x >> 3;

  // staging: instr i covers 16B-chunks [i*256 + tid]; chunk -> (row = c>>3, slot = c&7)
  const int srow = tid >> 3;                       // 0..31, +32 per instr
  const int sswz = ((tid & 7) ^ (srow & 7)) << 4;  // inverse-swizzled source slot
  const char* Ag = (const char*)chebT + (size_t)(nt * 128 + srow) * 6144 + sswz;
  const int btl = srow >> 4, so = srow & 15;
  const char* Bg = (const char*)hwt + (size_t)(ct * 8 + btl) * 98304 + (size_t)so * 6144 + sswz;
  char* Als = smem + w * 1024;
  char* Bls = smem + 16384 + w * 1024;

  // fragment reads
  const int r16 = lane & 15;
  const int c16 = lane >> 4;
  const int wr = (w >> 1) << 6;
  const int wc = (w & 1) << 6;
  const int axor = (r16 & 7) << 4;
  const char* Abase = smem + (wr + r16) * 128;
  const char* Bbase = smem + 16384 + (wc + r16) * 128;

  f32x4 acc[4][4];
  #pragma unroll
  for (int i = 0; i < 4; i++)
    #pragma unroll
    for (int j = 0; j < 4; j++) acc[i][j] = (f32x4){0.f, 0.f, 0.f, 0.f};

  for (int kt = 0; kt < 48; kt++) {
    __syncthreads();
    const char* a = Ag + kt * 128;
    const char* b = Bg + kt * 128;
    #pragma unroll
    for (int i = 0; i < 4; i++) GLOAD16(a + i * 196608, Als + i * 4096);
    #pragma unroll
    for (int i = 0; i < 4; i++) GLOAD16(b + i * 196608, Bls + i * 4096);
    __syncthreads();
    #pragma unroll
    for (int ksub = 0; ksub < 2; ksub++) {
      const int ko = (ksub * 64 + c16 * 16) ^ axor;
      bf16x8 af[4], bfr[4];
      #pragma unroll
      for (int i = 0; i < 4; i++) af[i] = *(const bf16x8*)(Abase + i * 2048 + ko);
      #pragma unroll
      for (int j = 0; j < 4; j++) bfr[j] = *(const bf16x8*)(Bbase + j * 2048 + ko);
      #pragma unroll
      for (int i = 0; i < 4; i++)
        #pragma unroll
        for (int j = 0; j < 4; j++)
          acc[i][j] = __builtin_amdgcn_mfma_f32_16x16x32_bf16(af[i], bfr[j], acc[i][j], 0, 0, 0);
    }
  }

  float bias = b_cheb[r16];
  #pragma unroll
  for (int j = 0; j < 4; j++) {
    int gcol = ct * 128 + wc + j * 16 + r16;
    size_t bt_g = (size_t)bt_base + (gcol >> 4);
    int o = gcol & 15;
    #pragma unroll
    for (int i = 0; i < 4; i++) {
      int n0 = nt * 128 + wr + i * 16 + c16 * 4;
      __hip_bfloat16* sp = sbuf + (bt_g * 1024 + n0) * 16 + o;
      #pragma unroll
      for (int r = 0; r < 4; r++)
        sp[r * 16] = __float2bfloat16(acc[i][j][r] + bias);
    }
  }
}

// ---------------------------------------------------------------------------
// K4: fused TCN2 (16->16, gated), sbuf bf16 -> h2 f32 (= d_out, pre-BN)
// ---------------------------------------------------------------------------
__global__ void __launch_bounds__(256) k_tcn2(
    const __hip_bfloat16* __restrict__ sbuf,
    const float* __restrict__ w1, const float* __restrict__ b1,
    const float* __restrict__ w2, const float* __restrict__ b2,
    const float* __restrict__ w3, const float* __restrict__ b3,
    float* __restrict__ h2) {
  __shared__ __align__(16) float s_w[2304];
  __shared__ float s_b[48];
  int tid = threadIdx.x;
  for (int i = tid; i < 768; i += 256) {
    int o = i / 48; int r = i % 48; int ci = r / 3; int dt = r % 3;
    int dst = dt * 256 + o * 16 + ci;
    s_w[dst] = w1[i]; s_w[768 + dst] = w2[i]; s_w[1536 + dst] = w3[i];
  }
  if (tid < 16) { s_b[tid] = b1[tid]; s_b[16 + tid] = b2[tid]; s_b[32 + tid] = b3[tid]; }
  __syncthreads();

  int bt2 = blockIdx.x >> 2;
  int n = ((blockIdx.x & 3) << 8) + tid;
  int b = bt2 / 20, t2 = bt2 % 20;

  float in[3][16];
  #pragma unroll
  for (int dt = 0; dt < 3; dt++) {
    const bf16x8* sp = reinterpret_cast<const bf16x8*>(
        sbuf + ((size_t)(b * 22 + t2 + dt) * 1024 + n) * 16);
    bf16x8 v0 = sp[0], v1 = sp[1];
    #pragma unroll
    for (int j = 0; j < 8; j++) { in[dt][j] = bf2f(v0[j]); in[dt][8 + j] = bf2f(v1[j]); }
  }

  const float4* w4 = reinterpret_cast<const float4*>(s_w);
  float res[16];
  #pragma unroll
  for (int o = 0; o < 16; o++) {
    float p = s_b[o], qz = s_b[16 + o], rz = s_b[32 + o];
    #pragma unroll
    for (int dt = 0; dt < 3; dt++) {
      #pragma unroll
      for (int cg = 0; cg < 4; cg++) {
        float4 wa = w4[(dt * 256 + o * 16) / 4 + cg];
        float4 wb = w4[(768 + dt * 256 + o * 16) / 4 + cg];
        float4 wc = w4[(1536 + dt * 256 + o * 16) / 4 + cg];
        const float* iv = &in[dt][cg * 4];
        p  = fmaf(iv[0], wa.x, fmaf(iv[1], wa.y, fmaf(iv[2], wa.z, fmaf(iv[3], wa.w, p))));
        qz = fmaf(iv[0], wb.x, fmaf(iv[1], wb.y, fmaf(iv[2], wb.z, fmaf(iv[3], wb.w, qz))));
        rz = fmaf(iv[0], wc.x, fmaf(iv[1], wc.y, fmaf(iv[2], wc.z, fmaf(iv[3], wc.w, rz))));
      }
    }
    res[o] = fmaf(p, sigm_f(qz), tanh_f(rz));
  }
  float4* hp = reinterpret_cast<float4*>(h2 + ((size_t)bt2 * 1024 + n) * 16);
  #pragma unroll
  for (int g = 0; g < 4; g++)
    hp[g] = (float4){res[g*4+0], res[g*4+1], res[g*4+2], res[g*4+3]};
}

// ---------------------------------------------------------------------------
// K5: per-node batch stats -> a[n], c[n]
// ---------------------------------------------------------------------------
__global__ void __launch_bounds__(256) k_stats(
    const float* __restrict__ h2, const float* __restrict__ gamma,
    const float* __restrict__ beta, float* __restrict__ ab) {
  int n = blockIdx.x;
  int tid = threadIdx.x;
  float s = 0.f, s2 = 0.f;
  int part = tid & 3;
  for (int bt2 = tid >> 2; bt2 < 640; bt2 += 64) {
    float4 v = *reinterpret_cast<const float4*>(h2 + ((size_t)bt2 * 1024 + n) * 16 + part * 4);
    s  += v.x + v.y + v.z + v.w;
    s2 += v.x*v.x + v.y*v.y + v.z*v.z + v.w*v.w;
  }
  #pragma unroll
  for (int off = 32; off; off >>= 1) { s += __shfl_down(s, off); s2 += __shfl_down(s2, off); }
  __shared__ float rs[4], rs2[4];
  if ((tid & 63) == 0) { rs[tid >> 6] = s; rs2[tid >> 6] = s2; }
  __syncthreads();
  if (tid == 0) {
    float S = rs[0] + rs[1] + rs[2] + rs[3];
    float S2 = rs2[0] + rs2[1] + rs2[2] + rs2[3];
    float mean = S * (1.f / 10240.f);
    float var = S2 * (1.f / 10240.f) - mean * mean;
    float a = gamma[n] * rsqrtf(var + 1e-5f);
    ab[n] = a;
    ab[1024 + n] = beta[n] - mean * a;
  }
}

// ---------------------------------------------------------------------------
// K6: in-place BN + ReLU on d_out
// ---------------------------------------------------------------------------
__global__ void __launch_bounds__(256) k_bnrelu(
    float* __restrict__ h2, const float* __restrict__ ab) {
  size_t i = (size_t)blockIdx.x * 256 + threadIdx.x;
  int n = (int)((i >> 2) & 1023);
  float a = ab[n], c = ab[1024 + n];
  float4* p = reinterpret_cast<float4*>(h2) + i;
  float4 v = *p;
  v.x = fmaxf(0.f, fmaf(v.x, a, c));
  v.y = fmaxf(0.f, fmaf(v.y, a, c));
  v.z = fmaxf(0.f, fmaf(v.z, a, c));
  v.w = fmaxf(0.f, fmaf(v.w, a, c));
  *p = v;
}

// ---------------------------------------------------------------------------
extern "C" void kernel_launch(void* const* d_in, const int* in_sizes, int n_in,
                              void* d_out, int out_size, void* d_ws, size_t ws_size,
                              hipStream_t stream) {
  const float* x     = (const float*)d_in[0];
  const float* cheb  = (const float*)d_in[1];
  const float* t1w1  = (const float*)d_in[2];
  const float* t1b1  = (const float*)d_in[3];
  const float* t1w2  = (const float*)d_in[4];
  const float* t1b2  = (const float*)d_in[5];
  const float* t1w3  = (const float*)d_in[6];
  const float* t1b3  = (const float*)d_in[7];
  const float* wch   = (const float*)d_in[8];
  const float* bch   = (const float*)d_in[9];
  const float* t2w1  = (const float*)d_in[10];
  const float* t2b1  = (const float*)d_in[11];
  const float* t2w2  = (const float*)d_in[12];
  const float* t2b2  = (const float*)d_in[13];
  const float* t2w3  = (const float*)d_in[14];
  const float* t2b3  = (const float*)d_in[15];
  const float* gam   = (const float*)d_in[16];
  const float* bet   = (const float*)d_in[17];

  char* ws = (char*)d_ws;
  __hip_bfloat16* chebT = (__hip_bfloat16*)ws;                   // 6,291,456 B
  __hip_bfloat16* sbuf  = (__hip_bfloat16*)(ws + 6291456);       // 23,068,672 B
  float*          ab    = (float*)(ws + 29360128);               // 8,192 B
  __hip_bfloat16* hwt   = (__hip_bfloat16*)(ws + 29368320);      // chunk buffer

  size_t avail = ws_size > 29368320 ? ws_size - 29368320 : 0;
  int maxch = (int)(avail / 98304);
  maxch &= ~7;                       // multiple of 8 (one col-tile = 8 bt)
  if (maxch > 704) maxch = 704;
  if (maxch < 8) maxch = 8;

  k_transpose_cheb<<<768, 256, 0, stream>>>(cheb, chebT);

  for (int bt0 = 0; bt0 < 704; bt0 += maxch) {
    int ch = (704 - bt0 < maxch) ? (704 - bt0) : maxch;
    k_tcn1_proj<<<ch * 4, 256, 0, stream>>>(x, t1w1, t1b1, t1w2, t1b2, t1w3, t1b3,
                                            wch, hwt, bt0);
    // grid = (ch/8 col-tiles) * 8 n-tiles; blockIdx%8 = n-tile (XCD-aligned)
    k_gemm<<<ch, 256, 0, stream>>>(chebT, hwt, bch, sbuf, bt0);
  }

  k_tcn2<<<640 * 4, 256, 0, stream>>>(sbuf, t2w1, t2b1, t2w2, t2b2, t2w3, t2b3,
                                      (float*)d_out);
  k_stats<<<1024, 256, 0, stream>>>((const float*)d_out, gam, bet, ab);
  k_bnrelu<<<10240, 256, 0, stream>>>((float*)d_out, ab);
}

// Round 3
// 240.024 us; speedup vs baseline: 2.1286x; 1.3226x over previous
//
#include <hip/hip_runtime.h>
#include <hip/hip_bf16.h>

using bf16x8 = __attribute__((ext_vector_type(8))) short;
using f32x4  = __attribute__((ext_vector_type(4))) float;

static __device__ __forceinline__ float bf2f(short s) {
  union { unsigned u; float f; } z;
  z.u = ((unsigned)(unsigned short)s) << 16;
  return z.f;
}
static __device__ __forceinline__ short f2bfs(float f) {
  union { __hip_bfloat16 h; short s; } u;
  u.h = __float2bfloat16(f);
  return u.s;
}
static __device__ __forceinline__ float frcp(float x) { return __builtin_amdgcn_rcpf(x); }
static __device__ __forceinline__ float sigm_f(float x) { return frcp(1.f + __expf(-x)); }
static __device__ __forceinline__ float tanh_f(float x) {
  float e = __expf(-2.f * fabsf(x));
  float t = (1.f - e) * frcp(1.f + e);
  return copysignf(t, x);
}

typedef const __attribute__((address_space(1))) unsigned int* gas_u32;
typedef __attribute__((address_space(3))) unsigned int* las_u32;
#define GLOAD16(gp, lp) __builtin_amdgcn_global_load_lds( \
    (gas_u32)(const void*)(gp), (las_u32)(void*)(lp), 16, 0, 0)

// ---------------------------------------------------------------------------
// K1: cheb [3][1024][1024] f32  ->  chebT bf16 [n][k*1024+m]
// ---------------------------------------------------------------------------
__global__ void __launch_bounds__(256) k_transpose_cheb(
    const float* __restrict__ cheb, __hip_bfloat16* __restrict__ chebT) {
  __shared__ float tile[64][65];
  int blk = blockIdx.x;
  int k = blk >> 8;
  int rem = blk & 255;
  int m0 = (rem >> 4) << 6;
  int n0 = (rem & 15) << 6;
  int tx = threadIdx.x & 63;
  int ty = threadIdx.x >> 6;
  const float* src = cheb + (size_t)k * 1024 * 1024;
  #pragma unroll
  for (int i = 0; i < 16; i++) {
    int ml = ty + i * 4;
    tile[ml][tx] = src[(size_t)(m0 + ml) * 1024 + n0 + tx];
  }
  __syncthreads();
  #pragma unroll
  for (int i = 0; i < 16; i++) {
    int nl = ty + i * 4;
    chebT[(size_t)(n0 + nl) * 3072 + k * 1024 + m0 + tx] =
        __float2bfloat16(tile[tx][nl]);
  }
}

// ---------------------------------------------------------------------------
// K2: fused TCN1 (1->64, gated) + w_cheb projection (64 -> 3*16)
// ---------------------------------------------------------------------------
__global__ void __launch_bounds__(256) k_tcn1_proj(
    const float* __restrict__ x,
    const float* __restrict__ w1, const float* __restrict__ b1,
    const float* __restrict__ w2, const float* __restrict__ b2,
    const float* __restrict__ w3, const float* __restrict__ b3,
    const float* __restrict__ wcheb,
    __hip_bfloat16* __restrict__ hwt, int bt0) {
  int tid = threadIdx.x;
  int btl = blockIdx.x >> 2;
  int m = ((blockIdx.x & 3) << 8) + tid;
  int bt = bt0 + btl;
  int b = bt / 22, t = bt % 22;
  const float* xp = x + (size_t)(b * 24 + t) * 1024 + m;
  float x0 = xp[0], x1 = xp[1024], x2 = xp[2048];

  float acc[48];
  #pragma unroll
  for (int j = 0; j < 48; j++) acc[j] = 0.f;

  const float4* wc4 = reinterpret_cast<const float4*>(wcheb);
  #pragma unroll 2
  for (int c = 0; c < 64; c++) {
    float p  = fmaf(x2, w1[c*3+2], fmaf(x1, w1[c*3+1], fmaf(x0, w1[c*3+0], b1[c])));
    float qz = fmaf(x2, w2[c*3+2], fmaf(x1, w2[c*3+1], fmaf(x0, w2[c*3+0], b2[c])));
    float rz = fmaf(x2, w3[c*3+2], fmaf(x1, w3[c*3+1], fmaf(x0, w3[c*3+0], b3[c])));
    float h = fmaf(p, sigm_f(qz), tanh_f(rz));
    #pragma unroll
    for (int k = 0; k < 3; k++) {
      #pragma unroll
      for (int og = 0; og < 4; og++) {
        float4 w4 = wc4[k*256 + c*4 + og];
        acc[k*16+og*4+0] = fmaf(h, w4.x, acc[k*16+og*4+0]);
        acc[k*16+og*4+1] = fmaf(h, w4.y, acc[k*16+og*4+1]);
        acc[k*16+og*4+2] = fmaf(h, w4.z, acc[k*16+og*4+2]);
        acc[k*16+og*4+3] = fmaf(h, w4.w, acc[k*16+og*4+3]);
      }
    }
  }
  __hip_bfloat16* hp = hwt + (size_t)btl * 49152 + m;
  #pragma unroll
  for (int k = 0; k < 3; k++)
    #pragma unroll
    for (int o = 0; o < 16; o++)
      hp[o * 3072 + k * 1024] = __float2bfloat16(acc[k*16+o]);
}

// ---------------------------------------------------------------------------
// K3: tiled GEMM  S[bt][n][o] = ChebT[n][km] * HWT[bt][o][km] + b_cheb[o]
// ---------------------------------------------------------------------------
__global__ void __launch_bounds__(256, 2) k_gemm(
    const __hip_bfloat16* __restrict__ chebT,
    const __hip_bfloat16* __restrict__ hwt,
    const float* __restrict__ b_cheb,
    __hip_bfloat16* __restrict__ sbuf,
    int bt_base) {
  __shared__ __align__(16) char smem[32768];
  const int tid = threadIdx.x;
  const int lane = tid & 63;
  const int w = tid >> 6;
  const int nt = blockIdx.x & 7;
  const int ct = blockIdx.x >> 3;

  const int srow = tid >> 3;
  const int sswz = ((tid & 7) ^ (srow & 7)) << 4;
  const char* Ag = (const char*)chebT + (size_t)(nt * 128 + srow) * 6144 + sswz;
  const int btl = srow >> 4, so = srow & 15;
  const char* Bg = (const char*)hwt + (size_t)(ct * 8 + btl) * 98304 + (size_t)so * 6144 + sswz;
  char* Als = smem + w * 1024;
  char* Bls = smem + 16384 + w * 1024;

  const int r16 = lane & 15;
  const int c16 = lane >> 4;
  const int wr = (w >> 1) << 6;
  const int wc = (w & 1) << 6;
  const int axor = (r16 & 7) << 4;
  const char* Abase = smem + (wr + r16) * 128;
  const char* Bbase = smem + 16384 + (wc + r16) * 128;

  f32x4 acc[4][4];
  #pragma unroll
  for (int i = 0; i < 4; i++)
    #pragma unroll
    for (int j = 0; j < 4; j++) acc[i][j] = (f32x4){0.f, 0.f, 0.f, 0.f};

  for (int kt = 0; kt < 48; kt++) {
    __syncthreads();
    const char* a = Ag + kt * 128;
    const char* b = Bg + kt * 128;
    #pragma unroll
    for (int i = 0; i < 4; i++) GLOAD16(a + i * 196608, Als + i * 4096);
    #pragma unroll
    for (int i = 0; i < 4; i++) GLOAD16(b + i * 196608, Bls + i * 4096);
    __syncthreads();
    #pragma unroll
    for (int ksub = 0; ksub < 2; ksub++) {
      const int ko = (ksub * 64 + c16 * 16) ^ axor;
      bf16x8 af[4], bfr[4];
      #pragma unroll
      for (int i = 0; i < 4; i++) af[i] = *(const bf16x8*)(Abase + i * 2048 + ko);
      #pragma unroll
      for (int j = 0; j < 4; j++) bfr[j] = *(const bf16x8*)(Bbase + j * 2048 + ko);
      #pragma unroll
      for (int i = 0; i < 4; i++)
        #pragma unroll
        for (int j = 0; j < 4; j++)
          acc[i][j] = __builtin_amdgcn_mfma_f32_16x16x32_bf16(af[i], bfr[j], acc[i][j], 0, 0, 0);
    }
  }

  float bias = b_cheb[r16];
  #pragma unroll
  for (int j = 0; j < 4; j++) {
    int gcol = ct * 128 + wc + j * 16 + r16;
    size_t bt_g = (size_t)bt_base + (gcol >> 4);
    int o = gcol & 15;
    #pragma unroll
    for (int i = 0; i < 4; i++) {
      int n0 = nt * 128 + wr + i * 16 + c16 * 4;
      __hip_bfloat16* sp = sbuf + (bt_g * 1024 + n0) * 16 + o;
      #pragma unroll
      for (int r = 0; r < 4; r++)
        sp[r * 16] = __float2bfloat16(acc[i][j][r] + bias);
    }
  }
}

// ---------------------------------------------------------------------------
// K4: fused TCN2 (16->16, gated) via MFMA.
//     out[bt2,n,j] = sum_{dt,ci} s[b,t2+dt,n,ci] * W[j][dt*16+ci],  j in [0,48)
//     A = sbuf rows (bf16, 16/row); B = weights gathered to regs; K=48 pad 64.
//     Block = 4 waves x 128 rows = 512 rows; grid = 640 bt2 * 2 halves.
// ---------------------------------------------------------------------------
__global__ void __launch_bounds__(256) k_tcn2(
    const __hip_bfloat16* __restrict__ sbuf,
    const float* __restrict__ w1, const float* __restrict__ b1,
    const float* __restrict__ w2, const float* __restrict__ b2,
    const float* __restrict__ w3, const float* __restrict__ b3,
    float* __restrict__ h2) {
  const int tid = threadIdx.x;
  const int lane = tid & 63, w = tid >> 6;
  const int r16 = lane & 15, kb = lane >> 4;
  const int half = blockIdx.x & 1;
  const int bt2 = blockIdx.x >> 1;
  const int b = bt2 / 20, t2 = bt2 % 20;

  // B fragments: col = r16 (output j within conv), k = kb*8+jj; W[j][k]=wt[j*48+ci*3+dt]
  bf16x8 bw[3][2];
  const float* wps[3] = {w1, w2, w3};
  #pragma unroll
  for (int c = 0; c < 3; c++) {
    #pragma unroll
    for (int jj = 0; jj < 8; jj++) {
      int k = kb * 8 + jj;
      bw[c][0][jj] = f2bfs(wps[c][r16 * 48 + (k & 15) * 3 + (k >> 4)]);
      bw[c][1][jj] = (kb < 2) ? f2bfs(wps[c][r16 * 48 + (kb * 8 + jj) * 3 + 2]) : (short)0;
    }
  }
  const float bp = b1[r16], bq = b2[r16], br = b3[r16];

  const char* sb = (const char*)sbuf;
  const size_t slice = (size_t)1024 * 32;
  const int rowbase = half * 512 + w * 128;
  // A-frag mfma#1: k=kb*8+jj -> dt = kb>>1, ci-half = kb&1
  const char* baseA = sb + (size_t)(b * 22 + t2 + (kb >> 1)) * slice
                      + (size_t)(rowbase + r16) * 32 + (kb & 1) * 16;
  // A-frag mfma#2: k=32+kb*8+jj -> dt = 2, ci-half = kb (valid kb<2)
  const char* baseC = sb + (size_t)(b * 22 + t2 + 2) * slice
                      + (size_t)(rowbase + r16) * 32 + (kb & 1) * 16;
  float* outp = h2 + ((size_t)bt2 * 1024 + rowbase + kb * 4) * 16 + r16;

  const f32x4 zro = {0.f, 0.f, 0.f, 0.f};
  #pragma unroll 2
  for (int i = 0; i < 8; i++) {
    bf16x8 a0 = *(const bf16x8*)(baseA + i * 512);
    bf16x8 a1{};
    if (kb < 2) a1 = *(const bf16x8*)(baseC + i * 512);
    f32x4 ap = __builtin_amdgcn_mfma_f32_16x16x32_bf16(a0, bw[0][0], zro, 0, 0, 0);
    f32x4 aq = __builtin_amdgcn_mfma_f32_16x16x32_bf16(a0, bw[1][0], zro, 0, 0, 0);
    f32x4 ar = __builtin_amdgcn_mfma_f32_16x16x32_bf16(a0, bw[2][0], zro, 0, 0, 0);
    ap = __builtin_amdgcn_mfma_f32_16x16x32_bf16(a1, bw[0][1], ap, 0, 0, 0);
    aq = __builtin_amdgcn_mfma_f32_16x16x32_bf16(a1, bw[1][1], aq, 0, 0, 0);
    ar = __builtin_amdgcn_mfma_f32_16x16x32_bf16(a1, bw[2][1], ar, 0, 0, 0);
    #pragma unroll
    for (int r = 0; r < 4; r++) {
      float h = fmaf(ap[r] + bp, sigm_f(aq[r] + bq), tanh_f(ar[r] + br));
      outp[(size_t)(i * 16 + r) * 16] = h;
    }
  }
}

// ---------------------------------------------------------------------------
// K5: per-node batch stats -> a[n], c[n]
// ---------------------------------------------------------------------------
__global__ void __launch_bounds__(256) k_stats(
    const float* __restrict__ h2, const float* __restrict__ gamma,
    const float* __restrict__ beta, float* __restrict__ ab) {
  int n = blockIdx.x;
  int tid = threadIdx.x;
  float s = 0.f, s2 = 0.f;
  int part = tid & 3;
  for (int bt2 = tid >> 2; bt2 < 640; bt2 += 64) {
    float4 v = *reinterpret_cast<const float4*>(h2 + ((size_t)bt2 * 1024 + n) * 16 + part * 4);
    s  += v.x + v.y + v.z + v.w;
    s2 += v.x*v.x + v.y*v.y + v.z*v.z + v.w*v.w;
  }
  #pragma unroll
  for (int off = 32; off; off >>= 1) { s += __shfl_down(s, off); s2 += __shfl_down(s2, off); }
  __shared__ float rs[4], rs2[4];
  if ((tid & 63) == 0) { rs[tid >> 6] = s; rs2[tid >> 6] = s2; }
  __syncthreads();
  if (tid == 0) {
    float S = rs[0] + rs[1] + rs[2] + rs[3];
    float S2 = rs2[0] + rs2[1] + rs2[2] + rs2[3];
    float mean = S * (1.f / 10240.f);
    float var = S2 * (1.f / 10240.f) - mean * mean;
    float a = gamma[n] * rsqrtf(var + 1e-5f);
    ab[n] = a;
    ab[1024 + n] = beta[n] - mean * a;
  }
}

// ---------------------------------------------------------------------------
// K6: in-place BN + ReLU on d_out
// ---------------------------------------------------------------------------
__global__ void __launch_bounds__(256) k_bnrelu(
    float* __restrict__ h2, const float* __restrict__ ab) {
  size_t i = (size_t)blockIdx.x * 256 + threadIdx.x;
  int n = (int)((i >> 2) & 1023);
  float a = ab[n], c = ab[1024 + n];
  float4* p = reinterpret_cast<float4*>(h2) + i;
  float4 v = *p;
  v.x = fmaxf(0.f, fmaf(v.x, a, c));
  v.y = fmaxf(0.f, fmaf(v.y, a, c));
  v.z = fmaxf(0.f, fmaf(v.z, a, c));
  v.w = fmaxf(0.f, fmaf(v.w, a, c));
  *p = v;
}

// ---------------------------------------------------------------------------
extern "C" void kernel_launch(void* const* d_in, const int* in_sizes, int n_in,
                              void* d_out, int out_size, void* d_ws, size_t ws_size,
                              hipStream_t stream) {
  const float* x     = (const float*)d_in[0];
  const float* cheb  = (const float*)d_in[1];
  const float* t1w1  = (const float*)d_in[2];
  const float* t1b1  = (const float*)d_in[3];
  const float* t1w2  = (const float*)d_in[4];
  const float* t1b2  = (const float*)d_in[5];
  const float* t1w3  = (const float*)d_in[6];
  const float* t1b3  = (const float*)d_in[7];
  const float* wch   = (const float*)d_in[8];
  const float* bch   = (const float*)d_in[9];
  const float* t2w1  = (const float*)d_in[10];
  const float* t2b1  = (const float*)d_in[11];
  const float* t2w2  = (const float*)d_in[12];
  const float* t2b2  = (const float*)d_in[13];
  const float* t2w3  = (const float*)d_in[14];
  const float* t2b3  = (const float*)d_in[15];
  const float* gam   = (const float*)d_in[16];
  const float* bet   = (const float*)d_in[17];

  char* ws = (char*)d_ws;
  __hip_bfloat16* chebT = (__hip_bfloat16*)ws;                   // 6,291,456 B
  __hip_bfloat16* sbuf  = (__hip_bfloat16*)(ws + 6291456);       // 23,068,672 B
  float*          ab    = (float*)(ws + 29360128);               // 8,192 B
  __hip_bfloat16* hwt   = (__hip_bfloat16*)(ws + 29368320);      // chunk buffer

  size_t avail = ws_size > 29368320 ? ws_size - 29368320 : 0;
  int maxch = (int)(avail / 98304);
  maxch &= ~7;
  if (maxch > 704) maxch = 704;
  if (maxch < 8) maxch = 8;

  k_transpose_cheb<<<768, 256, 0, stream>>>(cheb, chebT);

  for (int bt0 = 0; bt0 < 704; bt0 += maxch) {
    int ch = (704 - bt0 < maxch) ? (704 - bt0) : maxch;
    k_tcn1_proj<<<ch * 4, 256, 0, stream>>>(x, t1w1, t1b1, t1w2, t1b2, t1w3, t1b3,
                                            wch, hwt, bt0);
    k_gemm<<<ch, 256, 0, stream>>>(chebT, hwt, bch, sbuf, bt0);
  }

  k_tcn2<<<1280, 256, 0, stream>>>(sbuf, t2w1, t2b1, t2w2, t2b2, t2w3, t2b3,
                                   (float*)d_out);
  k_stats<<<1024, 256, 0, stream>>>((const float*)d_out, gam, bet, ab);
  k_bnrelu<<<10240, 256, 0, stream>>>((float*)d_out, ab);
}

// Round 4
// 209.656 us; speedup vs baseline: 2.4370x; 1.1448x over previous
//
#include <hip/hip_runtime.h>
#include <hip/hip_bf16.h>

using bf16x8 = __attribute__((ext_vector_type(8))) short;
using bf16x4 = __attribute__((ext_vector_type(4))) short;
using f32x4  = __attribute__((ext_vector_type(4))) float;

static __device__ __forceinline__ float bf2f(short s) {
  union { unsigned u; float f; } z;
  z.u = ((unsigned)(unsigned short)s) << 16;
  return z.f;
}
static __device__ __forceinline__ short f2bfs(float f) {
  union { __hip_bfloat16 h; short s; } u;
  u.h = __float2bfloat16(f);
  return u.s;
}
static __device__ __forceinline__ float frcp(float x) { return __builtin_amdgcn_rcpf(x); }
static __device__ __forceinline__ float sigm_f(float x) { return frcp(1.f + __expf(-x)); }
static __device__ __forceinline__ float tanh_f(float x) {
  float e = __expf(-2.f * fabsf(x));
  float t = (1.f - e) * frcp(1.f + e);
  return copysignf(t, x);
}

typedef const __attribute__((address_space(1))) unsigned int* gas_u32;
typedef __attribute__((address_space(3))) unsigned int* las_u32;
#define GLOAD16(gp, lp) __builtin_amdgcn_global_load_lds( \
    (gas_u32)(const void*)(gp), (las_u32)(void*)(lp), 16, 0, 0)

// ---------------------------------------------------------------------------
// K1: cheb [3][1024][1024] f32  ->  chebT bf16 [n][k*1024+m]
// ---------------------------------------------------------------------------
__global__ void __launch_bounds__(256) k_transpose_cheb(
    const float* __restrict__ cheb, __hip_bfloat16* __restrict__ chebT) {
  __shared__ float tile[64][65];
  int blk = blockIdx.x;
  int k = blk >> 8;
  int rem = blk & 255;
  int m0 = (rem >> 4) << 6;
  int n0 = (rem & 15) << 6;
  int tx = threadIdx.x & 63;
  int ty = threadIdx.x >> 6;
  const float* src = cheb + (size_t)k * 1024 * 1024;
  #pragma unroll
  for (int i = 0; i < 16; i++) {
    int ml = ty + i * 4;
    tile[ml][tx] = src[(size_t)(m0 + ml) * 1024 + n0 + tx];
  }
  __syncthreads();
  #pragma unroll
  for (int i = 0; i < 16; i++) {
    int nl = ty + i * 4;
    chebT[(size_t)(n0 + nl) * 3072 + k * 1024 + m0 + tx] =
        __float2bfloat16(tile[tx][nl]);
  }
}

// ---------------------------------------------------------------------------
// K2: fused TCN1 (1->64, gated) + w_cheb projection (64 -> 3*16) via MFMA.
//     Phase 1: thread computes h[m][0..63] (gated conv), packs bf16 into
//              LDS tile [256 m][64 c], chunk-XOR-swizzled (T2).
//     Phase 2: 4 waves, MFMA 16x16x32: A = LDS h-tile, B = w_cheb regs.
//     Output layout unchanged: hwt[btl][o*3072 + k*1024 + m].
// ---------------------------------------------------------------------------
__global__ void __launch_bounds__(256) k_tcn1_proj(
    const float* __restrict__ x,
    const float* __restrict__ w1, const float* __restrict__ b1,
    const float* __restrict__ w2, const float* __restrict__ b2,
    const float* __restrict__ w3, const float* __restrict__ b3,
    const float* __restrict__ wcheb,
    __hip_bfloat16* __restrict__ hwt, int bt0) {
  __shared__ __align__(16) char hls[32768];   // [256 rows][128 B] swizzled
  const int tid = threadIdx.x;
  const int lane = tid & 63, w = tid >> 6;
  const int r16 = lane & 15, kb = lane >> 4;
  const int btl = blockIdx.x >> 2;
  const int m0 = (blockIdx.x & 3) << 8;
  const int bt = bt0 + btl;
  const int b = bt / 22, t = bt % 22;

  const float* xp = x + (size_t)(b * 24 + t) * 1024 + m0 + tid;
  const float x0 = xp[0], x1 = xp[1024], x2 = xp[2048];

  // B fragments: col o = r16, k-elem c = ks*32 + kb*8 + jj; wcheb[k][c][o]
  bf16x8 bw[3][2];
  #pragma unroll
  for (int kk = 0; kk < 3; kk++)
    #pragma unroll
    for (int ks = 0; ks < 2; ks++)
      #pragma unroll
      for (int jj = 0; jj < 8; jj++)
        bw[kk][ks][jj] = f2bfs(wcheb[kk * 1024 + (ks * 32 + kb * 8 + jj) * 16 + r16]);

  // Phase 1: gated conv, 8 channels per chunk -> swizzled LDS
  const int rswz = (tid & 7) << 4;
  #pragma unroll
  for (int cg = 0; cg < 8; cg++) {
    bf16x8 hv;
    #pragma unroll
    for (int j = 0; j < 8; j++) {
      const int c = cg * 8 + j;
      float p  = fmaf(x2, w1[c*3+2], fmaf(x1, w1[c*3+1], fmaf(x0, w1[c*3+0], b1[c])));
      float qz = fmaf(x2, w2[c*3+2], fmaf(x1, w2[c*3+1], fmaf(x0, w2[c*3+0], b2[c])));
      float rz = fmaf(x2, w3[c*3+2], fmaf(x1, w3[c*3+1], fmaf(x0, w3[c*3+0], b3[c])));
      hv[j] = f2bfs(fmaf(p, sigm_f(qz), tanh_f(rz)));
    }
    *(bf16x8*)(hls + tid * 128 + ((cg << 4) ^ rswz)) = hv;
  }
  __syncthreads();

  // Phase 2: projection MFMA. Wave w owns rows [w*64, w*64+64).
  const char* Ab = hls + (w * 64 + r16) * 128;
  const int axor = (r16 & 7) << 4;
  f32x4 acc[4][3];
  #pragma unroll
  for (int mt = 0; mt < 4; mt++)
    #pragma unroll
    for (int kk = 0; kk < 3; kk++) acc[mt][kk] = (f32x4){0.f, 0.f, 0.f, 0.f};

  #pragma unroll
  for (int ks = 0; ks < 2; ks++) {
    #pragma unroll
    for (int mt = 0; mt < 4; mt++) {
      bf16x8 a = *(const bf16x8*)(Ab + mt * 2048 + ((((ks << 2) + kb) << 4) ^ axor));
      #pragma unroll
      for (int kk = 0; kk < 3; kk++)
        acc[mt][kk] = __builtin_amdgcn_mfma_f32_16x16x32_bf16(a, bw[kk][ks], acc[mt][kk], 0, 0, 0);
    }
  }

  // Epilogue: D col = o = r16, row (local) = kb*4 + r within 16-row tile
  __hip_bfloat16* hp = hwt + (size_t)btl * 49152 + r16 * 3072 + m0 + w * 64;
  #pragma unroll
  for (int kk = 0; kk < 3; kk++)
    #pragma unroll
    for (int mt = 0; mt < 4; mt++) {
      bf16x4 v;
      #pragma unroll
      for (int r = 0; r < 4; r++) v[r] = f2bfs(acc[mt][kk][r]);
      *(bf16x4*)(hp + kk * 1024 + mt * 16 + kb * 4) = v;
    }
}

// ---------------------------------------------------------------------------
// K3: tiled GEMM  S[bt][n][o] = ChebT[n][km] * HWT[bt][o][km] + b_cheb[o]
// ---------------------------------------------------------------------------
__global__ void __launch_bounds__(256, 2) k_gemm(
    const __hip_bfloat16* __restrict__ chebT,
    const __hip_bfloat16* __restrict__ hwt,
    const float* __restrict__ b_cheb,
    __hip_bfloat16* __restrict__ sbuf,
    int bt_base) {
  __shared__ __align__(16) char smem[32768];
  const int tid = threadIdx.x;
  const int lane = tid & 63;
  const int w = tid >> 6;
  const int nt = blockIdx.x & 7;
  const int ct = blockIdx.x >> 3;

  const int srow = tid >> 3;
  const int sswz = ((tid & 7) ^ (srow & 7)) << 4;
  const char* Ag = (const char*)chebT + (size_t)(nt * 128 + srow) * 6144 + sswz;
  const int btl = srow >> 4, so = srow & 15;
  const char* Bg = (const char*)hwt + (size_t)(ct * 8 + btl) * 98304 + (size_t)so * 6144 + sswz;
  char* Als = smem + w * 1024;
  char* Bls = smem + 16384 + w * 1024;

  const int r16 = lane & 15;
  const int c16 = lane >> 4;
  const int wr = (w >> 1) << 6;
  const int wc = (w & 1) << 6;
  const int axor = (r16 & 7) << 4;
  const char* Abase = smem + (wr + r16) * 128;
  const char* Bbase = smem + 16384 + (wc + r16) * 128;

  f32x4 acc[4][4];
  #pragma unroll
  for (int i = 0; i < 4; i++)
    #pragma unroll
    for (int j = 0; j < 4; j++) acc[i][j] = (f32x4){0.f, 0.f, 0.f, 0.f};

  for (int kt = 0; kt < 48; kt++) {
    __syncthreads();
    const char* a = Ag + kt * 128;
    const char* b = Bg + kt * 128;
    #pragma unroll
    for (int i = 0; i < 4; i++) GLOAD16(a + i * 196608, Als + i * 4096);
    #pragma unroll
    for (int i = 0; i < 4; i++) GLOAD16(b + i * 196608, Bls + i * 4096);
    __syncthreads();
    #pragma unroll
    for (int ksub = 0; ksub < 2; ksub++) {
      const int ko = (ksub * 64 + c16 * 16) ^ axor;
      bf16x8 af[4], bfr[4];
      #pragma unroll
      for (int i = 0; i < 4; i++) af[i] = *(const bf16x8*)(Abase + i * 2048 + ko);
      #pragma unroll
      for (int j = 0; j < 4; j++) bfr[j] = *(const bf16x8*)(Bbase + j * 2048 + ko);
      #pragma unroll
      for (int i = 0; i < 4; i++)
        #pragma unroll
        for (int j = 0; j < 4; j++)
          acc[i][j] = __builtin_amdgcn_mfma_f32_16x16x32_bf16(af[i], bfr[j], acc[i][j], 0, 0, 0);
    }
  }

  float bias = b_cheb[r16];
  #pragma unroll
  for (int j = 0; j < 4; j++) {
    int gcol = ct * 128 + wc + j * 16 + r16;
    size_t bt_g = (size_t)bt_base + (gcol >> 4);
    int o = gcol & 15;
    #pragma unroll
    for (int i = 0; i < 4; i++) {
      int n0 = nt * 128 + wr + i * 16 + c16 * 4;
      __hip_bfloat16* sp = sbuf + (bt_g * 1024 + n0) * 16 + o;
      #pragma unroll
      for (int r = 0; r < 4; r++)
        sp[r * 16] = __float2bfloat16(acc[i][j][r] + bias);
    }
  }
}

// ---------------------------------------------------------------------------
// K4: fused TCN2 (16->16, gated) via MFMA.
// ---------------------------------------------------------------------------
__global__ void __launch_bounds__(256) k_tcn2(
    const __hip_bfloat16* __restrict__ sbuf,
    const float* __restrict__ w1, const float* __restrict__ b1,
    const float* __restrict__ w2, const float* __restrict__ b2,
    const float* __restrict__ w3, const float* __restrict__ b3,
    float* __restrict__ h2) {
  const int tid = threadIdx.x;
  const int lane = tid & 63, w = tid >> 6;
  const int r16 = lane & 15, kb = lane >> 4;
  const int half = blockIdx.x & 1;
  const int bt2 = blockIdx.x >> 1;
  const int b = bt2 / 20, t2 = bt2 % 20;

  bf16x8 bw[3][2];
  const float* wps[3] = {w1, w2, w3};
  #pragma unroll
  for (int c = 0; c < 3; c++) {
    #pragma unroll
    for (int jj = 0; jj < 8; jj++) {
      int k = kb * 8 + jj;
      bw[c][0][jj] = f2bfs(wps[c][r16 * 48 + (k & 15) * 3 + (k >> 4)]);
      bw[c][1][jj] = (kb < 2) ? f2bfs(wps[c][r16 * 48 + (kb * 8 + jj) * 3 + 2]) : (short)0;
    }
  }
  const float bp = b1[r16], bq = b2[r16], br = b3[r16];

  const char* sb = (const char*)sbuf;
  const size_t slice = (size_t)1024 * 32;
  const int rowbase = half * 512 + w * 128;
  const char* baseA = sb + (size_t)(b * 22 + t2 + (kb >> 1)) * slice
                      + (size_t)(rowbase + r16) * 32 + (kb & 1) * 16;
  const char* baseC = sb + (size_t)(b * 22 + t2 + 2) * slice
                      + (size_t)(rowbase + r16) * 32 + (kb & 1) * 16;
  float* outp = h2 + ((size_t)bt2 * 1024 + rowbase + kb * 4) * 16 + r16;

  const f32x4 zro = {0.f, 0.f, 0.f, 0.f};
  #pragma unroll 2
  for (int i = 0; i < 8; i++) {
    bf16x8 a0 = *(const bf16x8*)(baseA + i * 512);
    bf16x8 a1{};
    if (kb < 2) a1 = *(const bf16x8*)(baseC + i * 512);
    f32x4 ap = __builtin_amdgcn_mfma_f32_16x16x32_bf16(a0, bw[0][0], zro, 0, 0, 0);
    f32x4 aq = __builtin_amdgcn_mfma_f32_16x16x32_bf16(a0, bw[1][0], zro, 0, 0, 0);
    f32x4 ar = __builtin_amdgcn_mfma_f32_16x16x32_bf16(a0, bw[2][0], zro, 0, 0, 0);
    ap = __builtin_amdgcn_mfma_f32_16x16x32_bf16(a1, bw[0][1], ap, 0, 0, 0);
    aq = __builtin_amdgcn_mfma_f32_16x16x32_bf16(a1, bw[1][1], aq, 0, 0, 0);
    ar = __builtin_amdgcn_mfma_f32_16x16x32_bf16(a1, bw[2][1], ar, 0, 0, 0);
    #pragma unroll
    for (int r = 0; r < 4; r++) {
      float h = fmaf(ap[r] + bp, sigm_f(aq[r] + bq), tanh_f(ar[r] + br));
      outp[(size_t)(i * 16 + r) * 16] = h;
    }
  }
}

// ---------------------------------------------------------------------------
// K5: per-node batch stats -> a[n], c[n]
// ---------------------------------------------------------------------------
__global__ void __launch_bounds__(256) k_stats(
    const float* __restrict__ h2, const float* __restrict__ gamma,
    const float* __restrict__ beta, float* __restrict__ ab) {
  int n = blockIdx.x;
  int tid = threadIdx.x;
  float s = 0.f, s2 = 0.f;
  int part = tid & 3;
  for (int bt2 = tid >> 2; bt2 < 640; bt2 += 64) {
    float4 v = *reinterpret_cast<const float4*>(h2 + ((size_t)bt2 * 1024 + n) * 16 + part * 4);
    s  += v.x + v.y + v.z + v.w;
    s2 += v.x*v.x + v.y*v.y + v.z*v.z + v.w*v.w;
  }
  #pragma unroll
  for (int off = 32; off; off >>= 1) { s += __shfl_down(s, off); s2 += __shfl_down(s2, off); }
  __shared__ float rs[4], rs2[4];
  if ((tid & 63) == 0) { rs[tid >> 6] = s; rs2[tid >> 6] = s2; }
  __syncthreads();
  if (tid == 0) {
    float S = rs[0] + rs[1] + rs[2] + rs[3];
    float S2 = rs2[0] + rs2[1] + rs2[2] + rs2[3];
    float mean = S * (1.f / 10240.f);
    float var = S2 * (1.f / 10240.f) - mean * mean;
    float a = gamma[n] * rsqrtf(var + 1e-5f);
    ab[n] = a;
    ab[1024 + n] = beta[n] - mean * a;
  }
}

// ---------------------------------------------------------------------------
// K6: in-place BN + ReLU on d_out
// ---------------------------------------------------------------------------
__global__ void __launch_bounds__(256) k_bnrelu(
    float* __restrict__ h2, const float* __restrict__ ab) {
  size_t i = (size_t)blockIdx.x * 256 + threadIdx.x;
  int n = (int)((i >> 2) & 1023);
  float a = ab[n], c = ab[1024 + n];
  float4* p = reinterpret_cast<float4*>(h2) + i;
  float4 v = *p;
  v.x = fmaxf(0.f, fmaf(v.x, a, c));
  v.y = fmaxf(0.f, fmaf(v.y, a, c));
  v.z = fmaxf(0.f, fmaf(v.z, a, c));
  v.w = fmaxf(0.f, fmaf(v.w, a, c));
  *p = v;
}

// ---------------------------------------------------------------------------
extern "C" void kernel_launch(void* const* d_in, const int* in_sizes, int n_in,
                              void* d_out, int out_size, void* d_ws, size_t ws_size,
                              hipStream_t stream) {
  const float* x     = (const float*)d_in[0];
  const float* cheb  = (const float*)d_in[1];
  const float* t1w1  = (const float*)d_in[2];
  const float* t1b1  = (const float*)d_in[3];
  const float* t1w2  = (const float*)d_in[4];
  const float* t1b2  = (const float*)d_in[5];
  const float* t1w3  = (const float*)d_in[6];
  const float* t1b3  = (const float*)d_in[7];
  const float* wch   = (const float*)d_in[8];
  const float* bch   = (const float*)d_in[9];
  const float* t2w1  = (const float*)d_in[10];
  const float* t2b1  = (const float*)d_in[11];
  const float* t2w2  = (const float*)d_in[12];
  const float* t2b2  = (const float*)d_in[13];
  const float* t2w3  = (const float*)d_in[14];
  const float* t2b3  = (const float*)d_in[15];
  const float* gam   = (const float*)d_in[16];
  const float* bet   = (const float*)d_in[17];

  char* ws = (char*)d_ws;
  __hip_bfloat16* chebT = (__hip_bfloat16*)ws;                   // 6,291,456 B
  __hip_bfloat16* sbuf  = (__hip_bfloat16*)(ws + 6291456);       // 23,068,672 B
  float*          ab    = (float*)(ws + 29360128);               // 8,192 B
  __hip_bfloat16* hwt   = (__hip_bfloat16*)(ws + 29368320);      // chunk buffer

  size_t avail = ws_size > 29368320 ? ws_size - 29368320 : 0;
  int maxch = (int)(avail / 98304);
  maxch &= ~7;
  if (maxch > 704) maxch = 704;
  if (maxch < 8) maxch = 8;

  k_transpose_cheb<<<768, 256, 0, stream>>>(cheb, chebT);

  for (int bt0 = 0; bt0 < 704; bt0 += maxch) {
    int ch = (704 - bt0 < maxch) ? (704 - bt0) : maxch;
    k_tcn1_proj<<<ch * 4, 256, 0, stream>>>(x, t1w1, t1b1, t1w2, t1b2, t1w3, t1b3,
                                            wch, hwt, bt0);
    k_gemm<<<ch, 256, 0, stream>>>(chebT, hwt, bch, sbuf, bt0);
  }

  k_tcn2<<<1280, 256, 0, stream>>>(sbuf, t2w1, t2b1, t2w2, t2b2, t2w3, t2b3,
                                   (float*)d_out);
  k_stats<<<1024, 256, 0, stream>>>((const float*)d_out, gam, bet, ab);
  k_bnrelu<<<10240, 256, 0, stream>>>((float*)d_out, ab);
}

// Round 5
// 186.915 us; speedup vs baseline: 2.7335x; 1.1217x over previous
//
#include <hip/hip_runtime.h>
#include <hip/hip_bf16.h>

using bf16x8 = __attribute__((ext_vector_type(8))) short;
using bf16x4 = __attribute__((ext_vector_type(4))) short;
using f32x4  = __attribute__((ext_vector_type(4))) float;

static __device__ __forceinline__ float bf2f(short s) {
  union { unsigned u; float f; } z;
  z.u = ((unsigned)(unsigned short)s) << 16;
  return z.f;
}
static __device__ __forceinline__ short f2bfs(float f) {
  union { __hip_bfloat16 h; short s; } u;
  u.h = __float2bfloat16(f);
  return u.s;
}
static __device__ __forceinline__ float frcp(float x) { return __builtin_amdgcn_rcpf(x); }
static __device__ __forceinline__ float sigm_f(float x) { return frcp(1.f + __expf(-x)); }
static __device__ __forceinline__ float tanh_f(float x) {
  float e = __expf(-2.f * fabsf(x));
  float t = (1.f - e) * frcp(1.f + e);
  return copysignf(t, x);
}

typedef const __attribute__((address_space(1))) unsigned int* gas_u32;
typedef __attribute__((address_space(3))) unsigned int* las_u32;
#define GLOAD16(gp, lp) __builtin_amdgcn_global_load_lds( \
    (gas_u32)(const void*)(gp), (las_u32)(void*)(lp), 16, 0, 0)

// ---------------------------------------------------------------------------
// K1: cheb [3][1024][1024] f32  ->  chebT bf16 [n][k*1024+m]
// ---------------------------------------------------------------------------
__global__ void __launch_bounds__(256) k_transpose_cheb(
    const float* __restrict__ cheb, __hip_bfloat16* __restrict__ chebT) {
  __shared__ float tile[64][65];
  int blk = blockIdx.x;
  int k = blk >> 8;
  int rem = blk & 255;
  int m0 = (rem >> 4) << 6;
  int n0 = (rem & 15) << 6;
  int tx = threadIdx.x & 63;
  int ty = threadIdx.x >> 6;
  const float* src = cheb + (size_t)k * 1024 * 1024;
  #pragma unroll
  for (int i = 0; i < 16; i++) {
    int ml = ty + i * 4;
    tile[ml][tx] = src[(size_t)(m0 + ml) * 1024 + n0 + tx];
  }
  __syncthreads();
  #pragma unroll
  for (int i = 0; i < 16; i++) {
    int nl = ty + i * 4;
    chebT[(size_t)(n0 + nl) * 3072 + k * 1024 + m0 + tx] =
        __float2bfloat16(tile[tx][nl]);
  }
}

// ---------------------------------------------------------------------------
// K2: fused TCN1 (1->64, gated) + w_cheb projection (64 -> 3*16) via MFMA.
// ---------------------------------------------------------------------------
__global__ void __launch_bounds__(256) k_tcn1_proj(
    const float* __restrict__ x,
    const float* __restrict__ w1, const float* __restrict__ b1,
    const float* __restrict__ w2, const float* __restrict__ b2,
    const float* __restrict__ w3, const float* __restrict__ b3,
    const float* __restrict__ wcheb,
    __hip_bfloat16* __restrict__ hwt, int bt0) {
  __shared__ __align__(16) char hls[32768];   // [256 rows][128 B] swizzled
  const int tid = threadIdx.x;
  const int lane = tid & 63, w = tid >> 6;
  const int r16 = lane & 15, kb = lane >> 4;
  const int btl = blockIdx.x >> 2;
  const int m0 = (blockIdx.x & 3) << 8;
  const int bt = bt0 + btl;
  const int b = bt / 22, t = bt % 22;

  const float* xp = x + (size_t)(b * 24 + t) * 1024 + m0 + tid;
  const float x0 = xp[0], x1 = xp[1024], x2 = xp[2048];

  // B fragments: col o = r16, k-elem c = ks*32 + kb*8 + jj; wcheb[k][c][o]
  bf16x8 bw[3][2];
  #pragma unroll
  for (int kk = 0; kk < 3; kk++)
    #pragma unroll
    for (int ks = 0; ks < 2; ks++)
      #pragma unroll
      for (int jj = 0; jj < 8; jj++)
        bw[kk][ks][jj] = f2bfs(wcheb[kk * 1024 + (ks * 32 + kb * 8 + jj) * 16 + r16]);

  // Phase 1: gated conv, 8 channels per chunk -> swizzled LDS
  const int rswz = (tid & 7) << 4;
  #pragma unroll
  for (int cg = 0; cg < 8; cg++) {
    bf16x8 hv;
    #pragma unroll
    for (int j = 0; j < 8; j++) {
      const int c = cg * 8 + j;
      float p  = fmaf(x2, w1[c*3+2], fmaf(x1, w1[c*3+1], fmaf(x0, w1[c*3+0], b1[c])));
      float qz = fmaf(x2, w2[c*3+2], fmaf(x1, w2[c*3+1], fmaf(x0, w2[c*3+0], b2[c])));
      float rz = fmaf(x2, w3[c*3+2], fmaf(x1, w3[c*3+1], fmaf(x0, w3[c*3+0], b3[c])));
      hv[j] = f2bfs(fmaf(p, sigm_f(qz), tanh_f(rz)));
    }
    *(bf16x8*)(hls + tid * 128 + ((cg << 4) ^ rswz)) = hv;
  }
  __syncthreads();

  // Phase 2: projection MFMA. Wave w owns rows [w*64, w*64+64).
  const char* Ab = hls + (w * 64 + r16) * 128;
  const int axor = (r16 & 7) << 4;
  f32x4 acc[4][3];
  #pragma unroll
  for (int mt = 0; mt < 4; mt++)
    #pragma unroll
    for (int kk = 0; kk < 3; kk++) acc[mt][kk] = (f32x4){0.f, 0.f, 0.f, 0.f};

  #pragma unroll
  for (int ks = 0; ks < 2; ks++) {
    #pragma unroll
    for (int mt = 0; mt < 4; mt++) {
      bf16x8 a = *(const bf16x8*)(Ab + mt * 2048 + ((((ks << 2) + kb) << 4) ^ axor));
      #pragma unroll
      for (int kk = 0; kk < 3; kk++)
        acc[mt][kk] = __builtin_amdgcn_mfma_f32_16x16x32_bf16(a, bw[kk][ks], acc[mt][kk], 0, 0, 0);
    }
  }

  __hip_bfloat16* hp = hwt + (size_t)btl * 49152 + r16 * 3072 + m0 + w * 64;
  #pragma unroll
  for (int kk = 0; kk < 3; kk++)
    #pragma unroll
    for (int mt = 0; mt < 4; mt++) {
      bf16x4 v;
      #pragma unroll
      for (int r = 0; r < 4; r++) v[r] = f2bfs(acc[mt][kk][r]);
      *(bf16x4*)(hp + kk * 1024 + mt * 16 + kb * 4) = v;
    }
}

// ---------------------------------------------------------------------------
// K3: tiled GEMM  S[bt][n][o] = ChebT[n][km] * HWT[bt][o][km] + b_cheb[o]
//     128x128 tile, BK=64, 4 waves. XCD partition: 8 XCDs = 2 nt-groups x
//     4 ct-groups -> each XCD owns (4 nt x 22 ct). A-set 3.1MB ~L2-resident;
//     each B-panel shared by 4 dispatch-adjacent blocks on ONE XCD (was 8
//     XCDs -> 8x L2 fill duplication).
// ---------------------------------------------------------------------------
__global__ void __launch_bounds__(256, 2) k_gemm(
    const __hip_bfloat16* __restrict__ chebT,
    const __hip_bfloat16* __restrict__ hwt,
    const float* __restrict__ b_cheb,
    __hip_bfloat16* __restrict__ sbuf,
    int bt_base) {
  __shared__ __align__(16) char smem[32768];
  const int tid = threadIdx.x;
  const int lane = tid & 63;
  const int w = tid >> 6;

  int nt, ct;
  if (gridDim.x == 704) {
    const int xcd = blockIdx.x & 7;      // HW round-robins blockIdx across XCDs
    const int idx = blockIdx.x >> 3;     // 0..87 within this XCD
    nt = ((xcd >> 2) << 2) + (idx & 3);  // nt-group {0..3} or {4..7}
    ct = (xcd & 3) * 22 + (idx >> 2);    // ct-group of 22
  } else {
    nt = blockIdx.x & 7;
    ct = blockIdx.x >> 3;
  }

  const int srow = tid >> 3;
  const int sswz = ((tid & 7) ^ (srow & 7)) << 4;
  const char* Ag = (const char*)chebT + (size_t)(nt * 128 + srow) * 6144 + sswz;
  const int btl = srow >> 4, so = srow & 15;
  const char* Bg = (const char*)hwt + (size_t)(ct * 8 + btl) * 98304 + (size_t)so * 6144 + sswz;
  char* Als = smem + w * 1024;
  char* Bls = smem + 16384 + w * 1024;

  const int r16 = lane & 15;
  const int c16 = lane >> 4;
  const int wr = (w >> 1) << 6;
  const int wc = (w & 1) << 6;
  const int axor = (r16 & 7) << 4;
  const char* Abase = smem + (wr + r16) * 128;
  const char* Bbase = smem + 16384 + (wc + r16) * 128;

  f32x4 acc[4][4];
  #pragma unroll
  for (int i = 0; i < 4; i++)
    #pragma unroll
    for (int j = 0; j < 4; j++) acc[i][j] = (f32x4){0.f, 0.f, 0.f, 0.f};

  for (int kt = 0; kt < 48; kt++) {
    __syncthreads();
    const char* a = Ag + kt * 128;
    const char* b = Bg + kt * 128;
    #pragma unroll
    for (int i = 0; i < 4; i++) GLOAD16(a + i * 196608, Als + i * 4096);
    #pragma unroll
    for (int i = 0; i < 4; i++) GLOAD16(b + i * 196608, Bls + i * 4096);
    __syncthreads();
    #pragma unroll
    for (int ksub = 0; ksub < 2; ksub++) {
      const int ko = (ksub * 64 + c16 * 16) ^ axor;
      bf16x8 af[4], bfr[4];
      #pragma unroll
      for (int i = 0; i < 4; i++) af[i] = *(const bf16x8*)(Abase + i * 2048 + ko);
      #pragma unroll
      for (int j = 0; j < 4; j++) bfr[j] = *(const bf16x8*)(Bbase + j * 2048 + ko);
      #pragma unroll
      for (int i = 0; i < 4; i++)
        #pragma unroll
        for (int j = 0; j < 4; j++)
          acc[i][j] = __builtin_amdgcn_mfma_f32_16x16x32_bf16(af[i], bfr[j], acc[i][j], 0, 0, 0);
    }
  }

  float bias = b_cheb[r16];
  #pragma unroll
  for (int j = 0; j < 4; j++) {
    int gcol = ct * 128 + wc + j * 16 + r16;
    size_t bt_g = (size_t)bt_base + (gcol >> 4);
    int o = gcol & 15;
    #pragma unroll
    for (int i = 0; i < 4; i++) {
      int n0 = nt * 128 + wr + i * 16 + c16 * 4;
      __hip_bfloat16* sp = sbuf + (bt_g * 1024 + n0) * 16 + o;
      #pragma unroll
      for (int r = 0; r < 4; r++)
        sp[r * 16] = __float2bfloat16(acc[i][j][r] + bias);
    }
  }
}

// ---------------------------------------------------------------------------
// K4: fused TCN2 (16->16, gated) via MFMA.
// ---------------------------------------------------------------------------
__global__ void __launch_bounds__(256) k_tcn2(
    const __hip_bfloat16* __restrict__ sbuf,
    const float* __restrict__ w1, const float* __restrict__ b1,
    const float* __restrict__ w2, const float* __restrict__ b2,
    const float* __restrict__ w3, const float* __restrict__ b3,
    float* __restrict__ h2) {
  const int tid = threadIdx.x;
  const int lane = tid & 63, w = tid >> 6;
  const int r16 = lane & 15, kb = lane >> 4;
  const int half = blockIdx.x & 1;
  const int bt2 = blockIdx.x >> 1;
  const int b = bt2 / 20, t2 = bt2 % 20;

  bf16x8 bw[3][2];
  const float* wps[3] = {w1, w2, w3};
  #pragma unroll
  for (int c = 0; c < 3; c++) {
    #pragma unroll
    for (int jj = 0; jj < 8; jj++) {
      int k = kb * 8 + jj;
      bw[c][0][jj] = f2bfs(wps[c][r16 * 48 + (k & 15) * 3 + (k >> 4)]);
      bw[c][1][jj] = (kb < 2) ? f2bfs(wps[c][r16 * 48 + (kb * 8 + jj) * 3 + 2]) : (short)0;
    }
  }
  const float bp = b1[r16], bq = b2[r16], br = b3[r16];

  const char* sb = (const char*)sbuf;
  const size_t slice = (size_t)1024 * 32;
  const int rowbase = half * 512 + w * 128;
  const char* baseA = sb + (size_t)(b * 22 + t2 + (kb >> 1)) * slice
                      + (size_t)(rowbase + r16) * 32 + (kb & 1) * 16;
  const char* baseC = sb + (size_t)(b * 22 + t2 + 2) * slice
                      + (size_t)(rowbase + r16) * 32 + (kb & 1) * 16;
  float* outp = h2 + ((size_t)bt2 * 1024 + rowbase + kb * 4) * 16 + r16;

  const f32x4 zro = {0.f, 0.f, 0.f, 0.f};
  #pragma unroll 2
  for (int i = 0; i < 8; i++) {
    bf16x8 a0 = *(const bf16x8*)(baseA + i * 512);
    bf16x8 a1{};
    if (kb < 2) a1 = *(const bf16x8*)(baseC + i * 512);
    f32x4 ap = __builtin_amdgcn_mfma_f32_16x16x32_bf16(a0, bw[0][0], zro, 0, 0, 0);
    f32x4 aq = __builtin_amdgcn_mfma_f32_16x16x32_bf16(a0, bw[1][0], zro, 0, 0, 0);
    f32x4 ar = __builtin_amdgcn_mfma_f32_16x16x32_bf16(a0, bw[2][0], zro, 0, 0, 0);
    ap = __builtin_amdgcn_mfma_f32_16x16x32_bf16(a1, bw[0][1], ap, 0, 0, 0);
    aq = __builtin_amdgcn_mfma_f32_16x16x32_bf16(a1, bw[1][1], aq, 0, 0, 0);
    ar = __builtin_amdgcn_mfma_f32_16x16x32_bf16(a1, bw[2][1], ar, 0, 0, 0);
    #pragma unroll
    for (int r = 0; r < 4; r++) {
      float h = fmaf(ap[r] + bp, sigm_f(aq[r] + bq), tanh_f(ar[r] + br));
      outp[(size_t)(i * 16 + r) * 16] = h;
    }
  }
}

// ---------------------------------------------------------------------------
// K5: per-node batch stats -> a[n], c[n]
// ---------------------------------------------------------------------------
__global__ void __launch_bounds__(256) k_stats(
    const float* __restrict__ h2, const float* __restrict__ gamma,
    const float* __restrict__ beta, float* __restrict__ ab) {
  int n = blockIdx.x;
  int tid = threadIdx.x;
  float s = 0.f, s2 = 0.f;
  int part = tid & 3;
  for (int bt2 = tid >> 2; bt2 < 640; bt2 += 64) {
    float4 v = *reinterpret_cast<const float4*>(h2 + ((size_t)bt2 * 1024 + n) * 16 + part * 4);
    s  += v.x + v.y + v.z + v.w;
    s2 += v.x*v.x + v.y*v.y + v.z*v.z + v.w*v.w;
  }
  #pragma unroll
  for (int off = 32; off; off >>= 1) { s += __shfl_down(s, off); s2 += __shfl_down(s2, off); }
  __shared__ float rs[4], rs2[4];
  if ((tid & 63) == 0) { rs[tid >> 6] = s; rs2[tid >> 6] = s2; }
  __syncthreads();
  if (tid == 0) {
    float S = rs[0] + rs[1] + rs[2] + rs[3];
    float S2 = rs2[0] + rs2[1] + rs2[2] + rs2[3];
    float mean = S * (1.f / 10240.f);
    float var = S2 * (1.f / 10240.f) - mean * mean;
    float a = gamma[n] * rsqrtf(var + 1e-5f);
    ab[n] = a;
    ab[1024 + n] = beta[n] - mean * a;
  }
}

// ---------------------------------------------------------------------------
// K6: in-place BN + ReLU on d_out
// ---------------------------------------------------------------------------
__global__ void __launch_bounds__(256) k_bnrelu(
    float* __restrict__ h2, const float* __restrict__ ab) {
  size_t i = (size_t)blockIdx.x * 256 + threadIdx.x;
  int n = (int)((i >> 2) & 1023);
  float a = ab[n], c = ab[1024 + n];
  float4* p = reinterpret_cast<float4*>(h2) + i;
  float4 v = *p;
  v.x = fmaxf(0.f, fmaf(v.x, a, c));
  v.y = fmaxf(0.f, fmaf(v.y, a, c));
  v.z = fmaxf(0.f, fmaf(v.z, a, c));
  v.w = fmaxf(0.f, fmaf(v.w, a, c));
  *p = v;
}

// ---------------------------------------------------------------------------
extern "C" void kernel_launch(void* const* d_in, const int* in_sizes, int n_in,
                              void* d_out, int out_size, void* d_ws, size_t ws_size,
                              hipStream_t stream) {
  const float* x     = (const float*)d_in[0];
  const float* cheb  = (const float*)d_in[1];
  const float* t1w1  = (const float*)d_in[2];
  const float* t1b1  = (const float*)d_in[3];
  const float* t1w2  = (const float*)d_in[4];
  const float* t1b2  = (const float*)d_in[5];
  const float* t1w3  = (const float*)d_in[6];
  const float* t1b3  = (const float*)d_in[7];
  const float* wch   = (const float*)d_in[8];
  const float* bch   = (const float*)d_in[9];
  const float* t2w1  = (const float*)d_in[10];
  const float* t2b1  = (const float*)d_in[11];
  const float* t2w2  = (const float*)d_in[12];
  const float* t2b2  = (const float*)d_in[13];
  const float* t2w3  = (const float*)d_in[14];
  const float* t2b3  = (const float*)d_in[15];
  const float* gam   = (const float*)d_in[16];
  const float* bet   = (const float*)d_in[17];

  char* ws = (char*)d_ws;
  __hip_bfloat16* chebT = (__hip_bfloat16*)ws;                   // 6,291,456 B
  __hip_bfloat16* sbuf  = (__hip_bfloat16*)(ws + 6291456);       // 23,068,672 B
  float*          ab    = (float*)(ws + 29360128);               // 8,192 B
  __hip_bfloat16* hwt   = (__hip_bfloat16*)(ws + 29368320);      // chunk buffer

  size_t avail = ws_size > 29368320 ? ws_size - 29368320 : 0;
  int maxch = (int)(avail / 98304);
  maxch &= ~7;
  if (maxch > 704) maxch = 704;
  if (maxch < 8) maxch = 8;

  k_transpose_cheb<<<768, 256, 0, stream>>>(cheb, chebT);

  for (int bt0 = 0; bt0 < 704; bt0 += maxch) {
    int ch = (704 - bt0 < maxch) ? (704 - bt0) : maxch;
    k_tcn1_proj<<<ch * 4, 256, 0, stream>>>(x, t1w1, t1b1, t1w2, t1b2, t1w3, t1b3,
                                            wch, hwt, bt0);
    k_gemm<<<ch, 256, 0, stream>>>(chebT, hwt, bch, sbuf, bt0);
  }

  k_tcn2<<<1280, 256, 0, stream>>>(sbuf, t2w1, t2b1, t2w2, t2b2, t2w3, t2b3,
                                   (float*)d_out);
  k_stats<<<1024, 256, 0, stream>>>((const float*)d_out, gam, bet, ab);
  k_bnrelu<<<10240, 256, 0, stream>>>((float*)d_out, ab);
}